// Round 9
// baseline (501.235 us; speedup 1.0000x reference)
//
#include <hip/hip_runtime.h>

#define N_NODES 100000
#define N_EDGES 3200000
#define EPS 1e-5f
#define NODE_BLOCKS 391   // ceil(100000/256)

typedef float v2f __attribute__((ext_vector_type(2)));
static __device__ __forceinline__ v2f splat(float x) { v2f v; v.x = x; v.y = x; return v; }

// true XCD id of the executing wave [measured: learn_hip m09 — returns 0..7 on gfx950]
static __device__ __forceinline__ int xcc_id() {
    int x;
    asm volatile("s_getreg_b32 %0, hwreg(HW_REG_XCC_ID, 0, 4)" : "=s"(x));
    return x & 7;
}

// ---- workspace layout (bytes) ----
#define OFF_STATS   0          // 8 doubles (bn sums)                [zeroed]
#define OFF_CNT8    1024       // int[8*100000] per-XCD histograms   [zeroed]
#define OFF_ROWPTR  3201024    // int[100001]
#define OFF_INVCNT  3601664    // float[100000]
#define OFF_BASE8   4001664    // int[100000*8] absolute CSR base per (node,xcd)
#define OFF_XN      7201664    // float4[100000]
#define OFF_AGG1    8801664    // float2[100000]
#define OFF_RANK    9601664    // int[3200000] packed (xcc<<28)|localrank
#define OFF_BSUM    22401664   // int[391]
#define OFF_BOFF    22403712   // int[391]
#define OFF_W1T     22405760   // transposed weights
#define OFF_W2T     22406784
#define OFF_V1T     22410880
#define OFF_V2T     22411392
#define OFF_HE_EDGE 22415616   // float2[3200000] enc out, edge order (25.6 MB)
#define OFF_HE_CSR  48015616   // float2[3200000] enc out, CSR order  (25.6 MB)
// hd (float4[3200000], 51.2 MB) aliases [OFF_HE_EDGE, OFF_HE_CSR+25.6MB):
// he_edge dead after k_place, he_csr dead after k_reduce_enc.
#define OFF_HD      22415616
// total ≈ 73.6 MB

__global__ __launch_bounds__(256) void k_bn_stats(const float* __restrict__ x,
                                                  double* __restrict__ stats) {
    int i = blockIdx.x * 256 + threadIdx.x;
    float4 v = make_float4(0.f, 0.f, 0.f, 0.f);
    if (i < N_NODES) v = ((const float4*)x)[i];
    double a[8];
    a[0] = v.x; a[1] = v.y; a[2] = v.z; a[3] = v.w;
    a[4] = (double)v.x * v.x; a[5] = (double)v.y * v.y;
    a[6] = (double)v.z * v.z; a[7] = (double)v.w * v.w;
    #pragma unroll
    for (int off = 32; off > 0; off >>= 1) {
        #pragma unroll
        for (int j = 0; j < 8; j++) a[j] += __shfl_down(a[j], off);
    }
    __shared__ double smem[4][8];
    int wave = threadIdx.x >> 6;
    int lane = threadIdx.x & 63;
    if (lane == 0) {
        #pragma unroll
        for (int j = 0; j < 8; j++) smem[wave][j] = a[j];
    }
    __syncthreads();
    if (threadIdx.x == 0) {
        #pragma unroll
        for (int j = 0; j < 8; j++) {
            double t = smem[0][j] + smem[1][j] + smem[2][j] + smem[3][j];
            atomicAdd(&stats[j], t);
        }
    }
}

__global__ __launch_bounds__(256) void k_normalize(const float* __restrict__ x,
                                                   const double* __restrict__ stats,
                                                   const float* __restrict__ bn_w,
                                                   const float* __restrict__ bn_b,
                                                   float* __restrict__ xn) {
    int i = blockIdx.x * 256 + threadIdx.x;
    if (i >= N_NODES) return;
    const double inv_n = 1.0 / (double)N_NODES;
    float mu[4], sc[4], sh[4];
    #pragma unroll
    for (int d = 0; d < 4; d++) {
        double m  = stats[d] * inv_n;
        double vr = stats[4 + d] * inv_n - m * m;
        float rs  = (float)(1.0 / sqrt(vr + (double)EPS));
        mu[d] = (float)m;
        sc[d] = rs * bn_w[d];
        sh[d] = bn_b[d];
    }
    float4 v = ((const float4*)x)[i];
    float4 o;
    o.x = (v.x - mu[0]) * sc[0] + sh[0];
    o.y = (v.y - mu[1]) * sc[1] + sh[1];
    o.z = (v.z - mu[2]) * sc[2] + sh[2];
    o.w = (v.w - mu[3]) * sc[3] + sh[3];
    ((float4*)xn)[i] = o;
}

// transpose weights so the streaming-j MLP form reads contiguous scalar rows
__global__ __launch_bounds__(1024) void k_prep(const float* __restrict__ ew1,
                                               const float* __restrict__ ew2,
                                               const float* __restrict__ dw1,
                                               const float* __restrict__ dw2,
                                               float* __restrict__ w1t,
                                               float* __restrict__ w2t,
                                               float* __restrict__ v1t,
                                               float* __restrict__ v2t) {
    int t = threadIdx.x;
    { int j = t >> 5, k = t & 31; w2t[j * 32 + k] = ew2[k * 32 + j]; }
    { int j = t >> 5, k = t & 31; v2t[j * 32 + k] = dw2[k * 32 + j]; }
    if (t < 256) { int j = t >> 3, k = t & 7; w1t[j * 8 + k] = ew1[k * 32 + j]; }
    if (t < 128) { int j = t >> 2, k = t & 3; v1t[j * 4 + k] = dw1[k * 32 + j]; }
}

// Encoder EdgeConv per-edge MLP (8->32->32->2, relu x3), 2 edges/thread via
// packed fp32. Rank atomics go to the executing XCD's replica with
// WORKGROUP (L2) scope -> serviced in the local L2, not memory-side.
__global__ __launch_bounds__(256, 4) void k_enc_edge(const float* __restrict__ xn,
                                                     const int* __restrict__ ei,
                                                     int* __restrict__ cnt8,
                                                     int* __restrict__ rank,
                                                     float2* __restrict__ he_edge,
                                                     const float* __restrict__ w1t,
                                                     const float* __restrict__ b1,
                                                     const float* __restrict__ w2t,
                                                     const float* __restrict__ b2,
                                                     const float* __restrict__ w3,
                                                     const float* __restrict__ b3) {
    int t = blockIdx.x * 256 + threadIdx.x;
    int e0 = 2 * t;
    if (e0 >= N_EDGES) return;   // N_EDGES even
    int xcc = xcc_id();
    int* mycnt = cnt8 + (size_t)xcc * N_NODES;
    int2 ss = *(const int2*)&ei[e0];
    int2 dd = *(const int2*)&ei[N_EDGES + e0];
    // L2-scope rank atomics issued early; results needed only at the end
    int rA = __hip_atomic_fetch_add(&mycnt[dd.x], 1, __ATOMIC_RELAXED, __HIP_MEMORY_SCOPE_WORKGROUP);
    int rB = __hip_atomic_fetch_add(&mycnt[dd.y], 1, __ATOMIC_RELAXED, __HIP_MEMORY_SCOPE_WORKGROUP);
    float4 xiA = ((const float4*)xn)[dd.x];
    float4 xjA = ((const float4*)xn)[ss.x];
    float4 xiB = ((const float4*)xn)[dd.y];
    float4 xjB = ((const float4*)xn)[ss.y];
    v2f in[8];
    in[0].x = xiA.x; in[0].y = xiB.x;
    in[1].x = xiA.y; in[1].y = xiB.y;
    in[2].x = xiA.z; in[2].y = xiB.z;
    in[3].x = xiA.w; in[3].y = xiB.w;
    in[4].x = xjA.x - xiA.x; in[4].y = xjB.x - xiB.x;
    in[5].x = xjA.y - xiA.y; in[5].y = xjB.y - xiB.y;
    in[6].x = xjA.z - xiA.z; in[6].y = xjB.z - xiB.z;
    in[7].x = xjA.w - xiA.w; in[7].y = xjB.w - xiB.w;

    v2f h1[32];
    #pragma unroll
    for (int j = 0; j < 32; j++) {
        v2f a = splat(b1[j]);
        #pragma unroll
        for (int k = 0; k < 8; k++) a = __builtin_elementwise_fma(in[k], splat(w1t[j * 8 + k]), a);
        h1[j] = __builtin_elementwise_max(a, splat(0.f));
    }

    v2f o0 = splat(b3[0]), o1 = splat(b3[1]);
    #pragma unroll
    for (int j = 0; j < 32; j++) {
        v2f a = splat(b2[j]);
        #pragma unroll
        for (int k = 0; k < 32; k++) a = __builtin_elementwise_fma(h1[k], splat(w2t[j * 32 + k]), a);
        a = __builtin_elementwise_max(a, splat(0.f));
        o0 = __builtin_elementwise_fma(a, splat(w3[2 * j + 0]), o0);
        o1 = __builtin_elementwise_fma(a, splat(w3[2 * j + 1]), o1);
    }
    o0 = __builtin_elementwise_max(o0, splat(0.f));
    o1 = __builtin_elementwise_max(o1, splat(0.f));
    ((float4*)he_edge)[t] = make_float4(o0.x, o1.x, o0.y, o1.y);
    *(int2*)&rank[e0] = make_int2((xcc << 28) | rA, (xcc << 28) | rB);
}

// scan phase A: fold 8 XCD replicas -> relative per-replica prefix (base8),
// total count, invcnt, per-block sums
__global__ __launch_bounds__(256) void k_scan_part(const int* __restrict__ cnt8,
                                                   int* __restrict__ bsum,
                                                   float* __restrict__ invcnt,
                                                   int* __restrict__ base8) {
    int i = blockIdx.x * 256 + threadIdx.x;
    int c = 0;
    if (i < N_NODES) {
        int pre[8];
        #pragma unroll
        for (int r = 0; r < 8; r++) { pre[r] = c; c += cnt8[r * N_NODES + i]; }
        #pragma unroll
        for (int r = 0; r < 8; r++) base8[i * 8 + r] = pre[r];
        invcnt[i] = 1.0f / (float)(c > 1 ? c : 1);
    }
    int s = c;
    #pragma unroll
    for (int off = 32; off > 0; off >>= 1) s += __shfl_down(s, off);
    __shared__ int wsum[4];
    int wave = threadIdx.x >> 6, lane = threadIdx.x & 63;
    if (lane == 0) wsum[wave] = s;
    __syncthreads();
    if (threadIdx.x == 0) bsum[blockIdx.x] = wsum[0] + wsum[1] + wsum[2] + wsum[3];
}

// scan phase B: single small block scans 391 block sums -> block offsets + total
__global__ __launch_bounds__(512) void k_scan_top(const int* __restrict__ bsum,
                                                  int* __restrict__ boff,
                                                  int* __restrict__ rowptr) {
    __shared__ int sm[512];
    int t = threadIdx.x;
    int v = (t < NODE_BLOCKS) ? bsum[t] : 0;
    sm[t] = v;
    __syncthreads();
    for (int off = 1; off < 512; off <<= 1) {
        int u = (t >= off) ? sm[t - off] : 0;
        __syncthreads();
        sm[t] += u;
        __syncthreads();
    }
    if (t < NODE_BLOCKS) boff[t] = (t == 0) ? 0 : sm[t - 1];
    if (t == 511) rowptr[N_NODES] = sm[511];
}

// scan phase C: in-block exclusive scan + block offset -> absolute rowptr;
// also promote base8 from relative to absolute (rowptr[i] + rel)
__global__ __launch_bounds__(256) void k_scan_local(const int* __restrict__ cnt8,
                                                    const int* __restrict__ boff,
                                                    int* __restrict__ rowptr,
                                                    int* __restrict__ base8) {
    int i = blockIdx.x * 256 + threadIdx.x;
    int c = 0;
    if (i < N_NODES) {
        #pragma unroll
        for (int r = 0; r < 8; r++) c += cnt8[r * N_NODES + i];
    }
    int lane = threadIdx.x & 63;
    int wave = threadIdx.x >> 6;
    int x = c;
    #pragma unroll
    for (int off = 1; off < 64; off <<= 1) {
        int u = __shfl_up(x, off);
        if (lane >= off) x += u;
    }
    __shared__ int wsum[4];
    if (lane == 63) wsum[wave] = x;
    __syncthreads();
    int wo = 0;
    #pragma unroll
    for (int w = 0; w < 4; w++) if (w < wave) wo += wsum[w];
    if (i < N_NODES) {
        int rp = boff[blockIdx.x] + wo + (x - c);
        rowptr[i] = rp;
        #pragma unroll
        for (int r = 0; r < 8; r++) base8[i * 8 + r] += rp;
    }
}

// scatter enc outputs into CSR order (pos from absolute base8 + packed rank)
__global__ __launch_bounds__(256) void k_place(const float2* __restrict__ he_edge,
                                               const int* __restrict__ ei,
                                               const int* __restrict__ base8,
                                               const int* __restrict__ rank,
                                               float2* __restrict__ he_csr) {
    int e = blockIdx.x * 256 + threadIdx.x;
    if (e >= N_EDGES) return;
    int d = ei[N_EDGES + e];
    int pk = rank[e];
    int r = ((unsigned)pk) >> 28;
    int lr = pk & 0x0FFFFFFF;
    he_csr[base8[(d << 3) | r] + lr] = he_edge[e];
}

// mean-aggregate encoder outputs per node (contiguous CSR segment)
__global__ __launch_bounds__(256) void k_reduce_enc(const float2* __restrict__ he,
                                                    const int* __restrict__ rowptr,
                                                    const float* __restrict__ invcnt,
                                                    float2* __restrict__ agg1) {
    int i = blockIdx.x * 256 + threadIdx.x;
    if (i >= N_NODES) return;
    int p0 = rowptr[i], p1 = rowptr[i + 1];
    float a0 = 0.f, a1 = 0.f;
    for (int p = p0; p < p1; p++) {
        float2 h = he[p];
        a0 += h.x; a1 += h.y;
    }
    float ic = invcnt[i];
    agg1[i] = make_float2(a0 * ic, a1 * ic);
}

// Decoder EdgeConv per-edge MLP (4->32->32->4, relu first two), 2 edges/thread
// packed fp32. Writes directly to CSR slots (scattered float4).
__global__ __launch_bounds__(256, 4) void k_dec_edge(const float2* __restrict__ henc,
                                                     const int* __restrict__ ei,
                                                     const int* __restrict__ base8,
                                                     const int* __restrict__ rank,
                                                     float4* __restrict__ hd,
                                                     const float* __restrict__ v1t,
                                                     const float* __restrict__ b1,
                                                     const float* __restrict__ v2t,
                                                     const float* __restrict__ b2,
                                                     const float* __restrict__ w3,
                                                     const float* __restrict__ b3) {
    int t = blockIdx.x * 256 + threadIdx.x;
    int e0 = 2 * t;
    if (e0 >= N_EDGES) return;
    int2 ss = *(const int2*)&ei[e0];
    int2 dd = *(const int2*)&ei[N_EDGES + e0];
    int2 pk = *(const int2*)&rank[e0];
    float2 hiA = henc[dd.x];
    float2 hjA = henc[ss.x];
    float2 hiB = henc[dd.y];
    float2 hjB = henc[ss.y];
    v2f in[4];
    in[0].x = hiA.x;         in[0].y = hiB.x;
    in[1].x = hiA.y;         in[1].y = hiB.y;
    in[2].x = hjA.x - hiA.x; in[2].y = hjB.x - hiB.x;
    in[3].x = hjA.y - hiA.y; in[3].y = hjB.y - hiB.y;

    v2f h1[32];
    #pragma unroll
    for (int j = 0; j < 32; j++) {
        v2f a = splat(b1[j]);
        #pragma unroll
        for (int k = 0; k < 4; k++) a = __builtin_elementwise_fma(in[k], splat(v1t[j * 4 + k]), a);
        h1[j] = __builtin_elementwise_max(a, splat(0.f));
    }

    v2f o0 = splat(b3[0]), o1 = splat(b3[1]), o2 = splat(b3[2]), o3 = splat(b3[3]);
    #pragma unroll
    for (int j = 0; j < 32; j++) {
        v2f a = splat(b2[j]);
        #pragma unroll
        for (int k = 0; k < 32; k++) a = __builtin_elementwise_fma(h1[k], splat(v2t[j * 32 + k]), a);
        a = __builtin_elementwise_max(a, splat(0.f));
        o0 = __builtin_elementwise_fma(a, splat(w3[4 * j + 0]), o0);
        o1 = __builtin_elementwise_fma(a, splat(w3[4 * j + 1]), o1);
        o2 = __builtin_elementwise_fma(a, splat(w3[4 * j + 2]), o2);
        o3 = __builtin_elementwise_fma(a, splat(w3[4 * j + 3]), o3);
    }
    int rA = ((unsigned)pk.x) >> 28, lA = pk.x & 0x0FFFFFFF;
    int rB = ((unsigned)pk.y) >> 28, lB = pk.y & 0x0FFFFFFF;
    int posA = base8[(dd.x << 3) | rA] + lA;
    int posB = base8[(dd.y << 3) | rB] + lB;
    hd[posA] = make_float4(o0.x, o1.x, o2.x, o3.x);  // no final relu
    hd[posB] = make_float4(o0.y, o1.y, o2.y, o3.y);
}

// mean-aggregate decoder outputs per node -> final output
__global__ __launch_bounds__(256) void k_reduce_dec(const float4* __restrict__ hd,
                                                    const int* __restrict__ rowptr,
                                                    const float* __restrict__ invcnt,
                                                    float4* __restrict__ out) {
    int i = blockIdx.x * 256 + threadIdx.x;
    if (i >= N_NODES) return;
    int p0 = rowptr[i], p1 = rowptr[i + 1];
    float a0 = 0.f, a1 = 0.f, a2 = 0.f, a3 = 0.f;
    for (int p = p0; p < p1; p++) {
        float4 h = hd[p];
        a0 += h.x; a1 += h.y; a2 += h.z; a3 += h.w;
    }
    float ic = invcnt[i];
    out[i] = make_float4(a0 * ic, a1 * ic, a2 * ic, a3 * ic);
}

extern "C" void kernel_launch(void* const* d_in, const int* in_sizes, int n_in,
                              void* d_out, int out_size, void* d_ws, size_t ws_size,
                              hipStream_t stream) {
    const float* x    = (const float*)d_in[0];
    const int*   ei   = (const int*)d_in[1];
    const float* bn_w = (const float*)d_in[2];
    const float* bn_b = (const float*)d_in[3];
    const float* ew1  = (const float*)d_in[4];
    const float* eb1  = (const float*)d_in[5];
    const float* ew2  = (const float*)d_in[6];
    const float* eb2  = (const float*)d_in[7];
    const float* ew3  = (const float*)d_in[8];
    const float* eb3  = (const float*)d_in[9];
    const float* dw1  = (const float*)d_in[10];
    const float* db1  = (const float*)d_in[11];
    const float* dw2  = (const float*)d_in[12];
    const float* db2  = (const float*)d_in[13];
    const float* dw3  = (const float*)d_in[14];
    const float* db3  = (const float*)d_in[15];

    char* ws = (char*)d_ws;
    double* stats   = (double*)(ws + OFF_STATS);
    int*    cnt8    = (int*)(ws + OFF_CNT8);
    int*    rowptr  = (int*)(ws + OFF_ROWPTR);
    float*  invcnt  = (float*)(ws + OFF_INVCNT);
    int*    base8   = (int*)(ws + OFF_BASE8);
    float*  xn      = (float*)(ws + OFF_XN);
    float2* agg1    = (float2*)(ws + OFF_AGG1);
    int*    rank    = (int*)(ws + OFF_RANK);
    int*    bsum    = (int*)(ws + OFF_BSUM);
    int*    boff    = (int*)(ws + OFF_BOFF);
    float*  w1t     = (float*)(ws + OFF_W1T);
    float*  w2t     = (float*)(ws + OFF_W2T);
    float*  v1t     = (float*)(ws + OFF_V1T);
    float*  v2t     = (float*)(ws + OFF_V2T);
    float2* he_edge = (float2*)(ws + OFF_HE_EDGE);
    float2* he_csr  = (float2*)(ws + OFF_HE_CSR);
    float4* hd      = (float4*)(ws + OFF_HD);   // aliases he buffers (dead by then)
    float4* out     = (float4*)d_out;

    // zero: stats (1 KB) + cnt8 (3.2 MB), contiguous
    hipMemsetAsync(ws, 0, OFF_CNT8 + 8 * N_NODES * sizeof(int), stream);

    const int edgeBlocks  = (N_EDGES + 255) / 256;        // 12500
    const int edgeBlocks2 = (N_EDGES / 2 + 255) / 256;    // 6250

    k_prep<<<1, 1024, 0, stream>>>(ew1, ew2, dw1, dw2, w1t, w2t, v1t, v2t);
    k_bn_stats<<<NODE_BLOCKS, 256, 0, stream>>>(x, stats);
    k_normalize<<<NODE_BLOCKS, 256, 0, stream>>>(x, stats, bn_w, bn_b, xn);
    k_enc_edge<<<edgeBlocks2, 256, 0, stream>>>(xn, ei, cnt8, rank, he_edge,
                                                w1t, eb1, w2t, eb2, ew3, eb3);
    k_scan_part<<<NODE_BLOCKS, 256, 0, stream>>>(cnt8, bsum, invcnt, base8);
    k_scan_top<<<1, 512, 0, stream>>>(bsum, boff, rowptr);
    k_scan_local<<<NODE_BLOCKS, 256, 0, stream>>>(cnt8, boff, rowptr, base8);
    k_place<<<edgeBlocks, 256, 0, stream>>>(he_edge, ei, base8, rank, he_csr);
    k_reduce_enc<<<NODE_BLOCKS, 256, 0, stream>>>(he_csr, rowptr, invcnt, agg1);
    k_dec_edge<<<edgeBlocks2, 256, 0, stream>>>(agg1, ei, base8, rank, hd,
                                                v1t, db1, v2t, db2, dw3, db3);
    k_reduce_dec<<<NODE_BLOCKS, 256, 0, stream>>>(hd, rowptr, invcnt, out);
}

// Round 10
// 433.177 us; speedup vs baseline: 1.1571x; 1.1571x over previous
//
#include <hip/hip_runtime.h>

#define N_NODES 100000
#define N_EDGES 3200000
#define EPS 1e-5f
#define NODE_BLOCKS 391   // ceil(100000/256)
#define NB 782            // buckets of 128 nodes (dst >> 7)
#define BSTRIDE 4608      // fixed bucket region: mean 4096 + 8 sigma
#define S1_BLOCKS 391     // x 8192 edges per block

typedef float v2f __attribute__((ext_vector_type(2)));
static __device__ __forceinline__ v2f splat(float x) { v2f v; v.x = x; v.y = x; return v; }

// ---- workspace layout (bytes) ----
#define OFF_STATS  0          // 8 doubles (bn sums)          [zeroed]
#define OFF_BCNT   1024       // int[782] bucket counts       [zeroed]
#define OFF_BBASE  5120       // int[783] bucket prefix
#define OFF_ROWPTR 8448       // int[100001]
#define OFF_INVCNT 408576     // float[100000]
#define OFF_XN     808576     // float4[100000]
#define OFF_AGG1   2408576    // float2[100000]
#define OFF_W1T    3208576    // transposed weights
#define OFF_W2T    3209600
#define OFF_V1T    3213696
#define OFF_V2T    3214208
#define OFF_BUCKET 3219456    // int2[782*4608] bucket regions (28.8 MB)
#define OFF_HE     32048128   // float2[3200000] enc out, CSR order (25.6 MB)
#define OFF_SD     57648128   // int2[3200000] (src,dst) CSR order  (25.6 MB)
// hd (float4[3.2M], 51.2 MB) aliases [OFF_BUCKET, OFF_BUCKET+54.4MB):
// bucket_buf dead after k_s2, he dead after k_reduce_enc; sd_csr (still
// live during dec) sits above hd's end (54,419,456 < 57,648,128).
#define OFF_HD     3219456
// total = 83,248,128 B ≈ 83.3 MB

__global__ __launch_bounds__(256) void k_bn_stats(const float* __restrict__ x,
                                                  double* __restrict__ stats) {
    int i = blockIdx.x * 256 + threadIdx.x;
    float4 v = make_float4(0.f, 0.f, 0.f, 0.f);
    if (i < N_NODES) v = ((const float4*)x)[i];
    double a[8];
    a[0] = v.x; a[1] = v.y; a[2] = v.z; a[3] = v.w;
    a[4] = (double)v.x * v.x; a[5] = (double)v.y * v.y;
    a[6] = (double)v.z * v.z; a[7] = (double)v.w * v.w;
    #pragma unroll
    for (int off = 32; off > 0; off >>= 1) {
        #pragma unroll
        for (int j = 0; j < 8; j++) a[j] += __shfl_down(a[j], off);
    }
    __shared__ double smem[4][8];
    int wave = threadIdx.x >> 6;
    int lane = threadIdx.x & 63;
    if (lane == 0) {
        #pragma unroll
        for (int j = 0; j < 8; j++) smem[wave][j] = a[j];
    }
    __syncthreads();
    if (threadIdx.x == 0) {
        #pragma unroll
        for (int j = 0; j < 8; j++) {
            double t = smem[0][j] + smem[1][j] + smem[2][j] + smem[3][j];
            atomicAdd(&stats[j], t);
        }
    }
}

__global__ __launch_bounds__(256) void k_normalize(const float* __restrict__ x,
                                                   const double* __restrict__ stats,
                                                   const float* __restrict__ bn_w,
                                                   const float* __restrict__ bn_b,
                                                   float* __restrict__ xn) {
    int i = blockIdx.x * 256 + threadIdx.x;
    if (i >= N_NODES) return;
    const double inv_n = 1.0 / (double)N_NODES;
    float mu[4], sc[4], sh[4];
    #pragma unroll
    for (int d = 0; d < 4; d++) {
        double m  = stats[d] * inv_n;
        double vr = stats[4 + d] * inv_n - m * m;
        float rs  = (float)(1.0 / sqrt(vr + (double)EPS));
        mu[d] = (float)m;
        sc[d] = rs * bn_w[d];
        sh[d] = bn_b[d];
    }
    float4 v = ((const float4*)x)[i];
    float4 o;
    o.x = (v.x - mu[0]) * sc[0] + sh[0];
    o.y = (v.y - mu[1]) * sc[1] + sh[1];
    o.z = (v.z - mu[2]) * sc[2] + sh[2];
    o.w = (v.w - mu[3]) * sc[3] + sh[3];
    ((float4*)xn)[i] = o;
}

// transpose weights so the streaming-j MLP form reads contiguous scalar rows
__global__ __launch_bounds__(1024) void k_prep(const float* __restrict__ ew1,
                                               const float* __restrict__ ew2,
                                               const float* __restrict__ dw1,
                                               const float* __restrict__ dw2,
                                               float* __restrict__ w1t,
                                               float* __restrict__ w2t,
                                               float* __restrict__ v1t,
                                               float* __restrict__ v2t) {
    int t = threadIdx.x;
    { int j = t >> 5, k = t & 31; w2t[j * 32 + k] = ew2[k * 32 + j]; }
    { int j = t >> 5, k = t & 31; v2t[j * 32 + k] = dw2[k * 32 + j]; }
    if (t < 256) { int j = t >> 3, k = t & 7; w1t[j * 8 + k] = ew1[k * 32 + j]; }
    if (t < 128) { int j = t >> 2, k = t & 3; v1t[j * 4 + k] = dw1[k * 32 + j]; }
}

// S1: bin edges by bucket = dst>>7 into fixed-stride regions.
// Per-block LDS histogram; ONE global fetch_add per (block,bucket) -> ~306k
// global atomics total (vs 3.2M per-edge); scatter via LDS running counters.
__global__ __launch_bounds__(256) void k_s1(const int* __restrict__ ei,
                                            int* __restrict__ bcnt,
                                            int2* __restrict__ bucket_buf) {
    __shared__ int hist[NB];
    __shared__ int run[NB];
    int tid = threadIdx.x;
    int e0 = blockIdx.x * 8192;
    for (int i = tid; i < NB; i += 256) hist[i] = 0;
    __syncthreads();
    for (int k = 0; k < 32; k++) {
        int e = e0 + k * 256 + tid;
        if (e < N_EDGES) atomicAdd(&hist[ei[N_EDGES + e] >> 7], 1);
    }
    __syncthreads();
    for (int i = tid; i < NB; i += 256) {
        int h = hist[i];
        run[i] = i * BSTRIDE + (h ? atomicAdd(&bcnt[i], h) : 0);
    }
    __syncthreads();
    for (int k = 0; k < 32; k++) {
        int e = e0 + k * 256 + tid;
        if (e < N_EDGES) {
            int s = ei[e];
            int d = ei[N_EDGES + e];
            int slot = atomicAdd(&run[d >> 7], 1);   // LDS
            bucket_buf[slot] = make_int2(s, d);
        }
    }
}

// SB: exclusive scan of 782 bucket counts -> bucket_base; rowptr[N]=N_EDGES
__global__ __launch_bounds__(1024) void k_sb(const int* __restrict__ bcnt,
                                             int* __restrict__ bbase,
                                             int* __restrict__ rowptr) {
    __shared__ int sm[1024];
    int t = threadIdx.x;
    sm[t] = (t < NB) ? bcnt[t] : 0;
    __syncthreads();
    for (int off = 1; off < 1024; off <<= 1) {
        int u = (t >= off) ? sm[t - off] : 0;
        __syncthreads();
        sm[t] += u;
        __syncthreads();
    }
    if (t < NB) bbase[t] = (t == 0) ? 0 : sm[t - 1];
    if (t == 0) { bbase[NB] = sm[NB - 1]; rowptr[N_NODES] = N_EDGES; }
}

// S2: one block per bucket. Exact per-node CSR via LDS counters only.
// Writes rowptr, invcnt, and compacted sd_csr (CSR order).
__global__ __launch_bounds__(256) void k_s2(const int2* __restrict__ bucket_buf,
                                            const int* __restrict__ bcnt,
                                            const int* __restrict__ bbase,
                                            int2* __restrict__ sd_csr,
                                            int* __restrict__ rowptr,
                                            float* __restrict__ invcnt) {
    __shared__ int cnt[128];
    __shared__ int sb[128];
    __shared__ int run[128];
    int b = blockIdx.x;
    int tid = threadIdx.x;
    int node0 = b << 7;
    int cb = bcnt[b];
    int rb = b * BSTRIDE;
    int gb = bbase[b];
    if (tid < 128) cnt[tid] = 0;
    __syncthreads();
    for (int p = tid; p < cb; p += 256)
        atomicAdd(&cnt[bucket_buf[rb + p].y - node0], 1);
    __syncthreads();
    if (tid == 0) {
        int acc = gb;
        for (int i = 0; i < 128; i++) { sb[i] = acc; acc += cnt[i]; }
    }
    __syncthreads();
    if (tid < 128) {
        int node = node0 + tid;
        if (node < N_NODES) {
            rowptr[node] = sb[tid];
            int c = cnt[tid];
            invcnt[node] = 1.0f / (float)(c > 1 ? c : 1);
        }
        run[tid] = sb[tid];
    }
    __syncthreads();
    for (int p = tid; p < cb; p += 256) {
        int2 sd = bucket_buf[rb + p];
        int slot = atomicAdd(&run[sd.y - node0], 1);   // LDS
        sd_csr[slot] = sd;
    }
}

// Encoder EdgeConv (8->32->32->2, relu x3) in CSR order, 2 slots/thread,
// packed fp32. Fully coalesced sd_csr loads and he stores; no atomics.
__global__ __launch_bounds__(256, 4) void k_enc_csr(const float* __restrict__ xn,
                                                    const int2* __restrict__ sd_csr,
                                                    float2* __restrict__ he,
                                                    const float* __restrict__ w1t,
                                                    const float* __restrict__ b1,
                                                    const float* __restrict__ w2t,
                                                    const float* __restrict__ b2,
                                                    const float* __restrict__ w3,
                                                    const float* __restrict__ b3) {
    int t = blockIdx.x * 256 + threadIdx.x;
    int p0 = 2 * t;
    if (p0 >= N_EDGES) return;   // N_EDGES even
    int4 sd = ((const int4*)sd_csr)[t];   // (sA, dA, sB, dB)
    float4 xiA = ((const float4*)xn)[sd.y];
    float4 xjA = ((const float4*)xn)[sd.x];
    float4 xiB = ((const float4*)xn)[sd.w];
    float4 xjB = ((const float4*)xn)[sd.z];
    v2f in[8];
    in[0].x = xiA.x; in[0].y = xiB.x;
    in[1].x = xiA.y; in[1].y = xiB.y;
    in[2].x = xiA.z; in[2].y = xiB.z;
    in[3].x = xiA.w; in[3].y = xiB.w;
    in[4].x = xjA.x - xiA.x; in[4].y = xjB.x - xiB.x;
    in[5].x = xjA.y - xiA.y; in[5].y = xjB.y - xiB.y;
    in[6].x = xjA.z - xiA.z; in[6].y = xjB.z - xiB.z;
    in[7].x = xjA.w - xiA.w; in[7].y = xjB.w - xiB.w;

    v2f h1[32];
    #pragma unroll
    for (int j = 0; j < 32; j++) {
        v2f a = splat(b1[j]);
        #pragma unroll
        for (int k = 0; k < 8; k++) a = __builtin_elementwise_fma(in[k], splat(w1t[j * 8 + k]), a);
        h1[j] = __builtin_elementwise_max(a, splat(0.f));
    }

    v2f o0 = splat(b3[0]), o1 = splat(b3[1]);
    #pragma unroll
    for (int j = 0; j < 32; j++) {
        v2f a = splat(b2[j]);
        #pragma unroll
        for (int k = 0; k < 32; k++) a = __builtin_elementwise_fma(h1[k], splat(w2t[j * 32 + k]), a);
        a = __builtin_elementwise_max(a, splat(0.f));
        o0 = __builtin_elementwise_fma(a, splat(w3[2 * j + 0]), o0);
        o1 = __builtin_elementwise_fma(a, splat(w3[2 * j + 1]), o1);
    }
    o0 = __builtin_elementwise_max(o0, splat(0.f));
    o1 = __builtin_elementwise_max(o1, splat(0.f));
    ((float4*)he)[t] = make_float4(o0.x, o1.x, o0.y, o1.y);
}

// mean-aggregate encoder outputs per node (contiguous CSR segment)
__global__ __launch_bounds__(256) void k_reduce_enc(const float2* __restrict__ he,
                                                    const int* __restrict__ rowptr,
                                                    const float* __restrict__ invcnt,
                                                    float2* __restrict__ agg1) {
    int i = blockIdx.x * 256 + threadIdx.x;
    if (i >= N_NODES) return;
    int p0 = rowptr[i], p1 = rowptr[i + 1];
    float a0 = 0.f, a1 = 0.f;
    for (int p = p0; p < p1; p++) {
        float2 h = he[p];
        a0 += h.x; a1 += h.y;
    }
    float ic = invcnt[i];
    agg1[i] = make_float2(a0 * ic, a1 * ic);
}

// Decoder EdgeConv (4->32->32->4, relu first two) in CSR order, 2 slots/thread,
// packed fp32. Fully coalesced in/out.
__global__ __launch_bounds__(256, 4) void k_dec_csr(const float2* __restrict__ henc,
                                                    const int2* __restrict__ sd_csr,
                                                    float4* __restrict__ hd,
                                                    const float* __restrict__ v1t,
                                                    const float* __restrict__ b1,
                                                    const float* __restrict__ v2t,
                                                    const float* __restrict__ b2,
                                                    const float* __restrict__ w3,
                                                    const float* __restrict__ b3) {
    int t = blockIdx.x * 256 + threadIdx.x;
    int p0 = 2 * t;
    if (p0 >= N_EDGES) return;
    int4 sd = ((const int4*)sd_csr)[t];   // (sA, dA, sB, dB)
    float2 hiA = henc[sd.y];
    float2 hjA = henc[sd.x];
    float2 hiB = henc[sd.w];
    float2 hjB = henc[sd.z];
    v2f in[4];
    in[0].x = hiA.x;         in[0].y = hiB.x;
    in[1].x = hiA.y;         in[1].y = hiB.y;
    in[2].x = hjA.x - hiA.x; in[2].y = hjB.x - hiB.x;
    in[3].x = hjA.y - hiA.y; in[3].y = hjB.y - hiB.y;

    v2f h1[32];
    #pragma unroll
    for (int j = 0; j < 32; j++) {
        v2f a = splat(b1[j]);
        #pragma unroll
        for (int k = 0; k < 4; k++) a = __builtin_elementwise_fma(in[k], splat(v1t[j * 4 + k]), a);
        h1[j] = __builtin_elementwise_max(a, splat(0.f));
    }

    v2f o0 = splat(b3[0]), o1 = splat(b3[1]), o2 = splat(b3[2]), o3 = splat(b3[3]);
    #pragma unroll
    for (int j = 0; j < 32; j++) {
        v2f a = splat(b2[j]);
        #pragma unroll
        for (int k = 0; k < 32; k++) a = __builtin_elementwise_fma(h1[k], splat(v2t[j * 32 + k]), a);
        a = __builtin_elementwise_max(a, splat(0.f));
        o0 = __builtin_elementwise_fma(a, splat(w3[4 * j + 0]), o0);
        o1 = __builtin_elementwise_fma(a, splat(w3[4 * j + 1]), o1);
        o2 = __builtin_elementwise_fma(a, splat(w3[4 * j + 2]), o2);
        o3 = __builtin_elementwise_fma(a, splat(w3[4 * j + 3]), o3);
    }
    hd[p0 + 0] = make_float4(o0.x, o1.x, o2.x, o3.x);  // no final relu
    hd[p0 + 1] = make_float4(o0.y, o1.y, o2.y, o3.y);
}

// mean-aggregate decoder outputs per node -> final output
__global__ __launch_bounds__(256) void k_reduce_dec(const float4* __restrict__ hd,
                                                    const int* __restrict__ rowptr,
                                                    const float* __restrict__ invcnt,
                                                    float4* __restrict__ out) {
    int i = blockIdx.x * 256 + threadIdx.x;
    if (i >= N_NODES) return;
    int p0 = rowptr[i], p1 = rowptr[i + 1];
    float a0 = 0.f, a1 = 0.f, a2 = 0.f, a3 = 0.f;
    for (int p = p0; p < p1; p++) {
        float4 h = hd[p];
        a0 += h.x; a1 += h.y; a2 += h.z; a3 += h.w;
    }
    float ic = invcnt[i];
    out[i] = make_float4(a0 * ic, a1 * ic, a2 * ic, a3 * ic);
}

extern "C" void kernel_launch(void* const* d_in, const int* in_sizes, int n_in,
                              void* d_out, int out_size, void* d_ws, size_t ws_size,
                              hipStream_t stream) {
    const float* x    = (const float*)d_in[0];
    const int*   ei   = (const int*)d_in[1];
    const float* bn_w = (const float*)d_in[2];
    const float* bn_b = (const float*)d_in[3];
    const float* ew1  = (const float*)d_in[4];
    const float* eb1  = (const float*)d_in[5];
    const float* ew2  = (const float*)d_in[6];
    const float* eb2  = (const float*)d_in[7];
    const float* ew3  = (const float*)d_in[8];
    const float* eb3  = (const float*)d_in[9];
    const float* dw1  = (const float*)d_in[10];
    const float* db1  = (const float*)d_in[11];
    const float* dw2  = (const float*)d_in[12];
    const float* db2  = (const float*)d_in[13];
    const float* dw3  = (const float*)d_in[14];
    const float* db3  = (const float*)d_in[15];

    char* ws = (char*)d_ws;
    double* stats      = (double*)(ws + OFF_STATS);
    int*    bcnt       = (int*)(ws + OFF_BCNT);
    int*    bbase      = (int*)(ws + OFF_BBASE);
    int*    rowptr     = (int*)(ws + OFF_ROWPTR);
    float*  invcnt     = (float*)(ws + OFF_INVCNT);
    float*  xn         = (float*)(ws + OFF_XN);
    float2* agg1       = (float2*)(ws + OFF_AGG1);
    float*  w1t        = (float*)(ws + OFF_W1T);
    float*  w2t        = (float*)(ws + OFF_W2T);
    float*  v1t        = (float*)(ws + OFF_V1T);
    float*  v2t        = (float*)(ws + OFF_V2T);
    int2*   bucket_buf = (int2*)(ws + OFF_BUCKET);
    float2* he         = (float2*)(ws + OFF_HE);
    int2*   sd_csr     = (int2*)(ws + OFF_SD);
    float4* hd         = (float4*)(ws + OFF_HD);   // aliases bucket_buf+he (dead)
    float4* out        = (float4*)d_out;

    // zero: stats + bucket counts, contiguous [0, 5120)
    hipMemsetAsync(ws, 0, 5120, stream);

    const int edgeBlocks2 = (N_EDGES / 2 + 255) / 256;    // 6250

    k_prep<<<1, 1024, 0, stream>>>(ew1, ew2, dw1, dw2, w1t, w2t, v1t, v2t);
    k_bn_stats<<<NODE_BLOCKS, 256, 0, stream>>>(x, stats);
    k_normalize<<<NODE_BLOCKS, 256, 0, stream>>>(x, stats, bn_w, bn_b, xn);
    k_s1<<<S1_BLOCKS, 256, 0, stream>>>(ei, bcnt, bucket_buf);
    k_sb<<<1, 1024, 0, stream>>>(bcnt, bbase, rowptr);
    k_s2<<<NB, 256, 0, stream>>>(bucket_buf, bcnt, bbase, sd_csr, rowptr, invcnt);
    k_enc_csr<<<edgeBlocks2, 256, 0, stream>>>(xn, sd_csr, he, w1t, eb1, w2t, eb2, ew3, eb3);
    k_reduce_enc<<<NODE_BLOCKS, 256, 0, stream>>>(he, rowptr, invcnt, agg1);
    k_dec_csr<<<edgeBlocks2, 256, 0, stream>>>(agg1, sd_csr, hd, v1t, db1, v2t, db2, dw3, db3);
    k_reduce_dec<<<NODE_BLOCKS, 256, 0, stream>>>(hd, rowptr, invcnt, out);
}